// Round 7
// baseline (607.443 us; speedup 1.0000x reference)
//
#include <hip/hip_runtime.h>
#include <hip/hip_bf16.h>
#include <stdint.h>

// ---------------------------------------------------------------------------
// W8A16 linear: out[M,N] = (A[M,K] fp32) x (W[N,K] int8->bf16)^T * scales[N] + bias[N]
// M=8192, N=4096, K=4096.  Prepass converts A,W -> bf16 in d_ws, then a
// 256x256-tile GEMM. R7: 2-barrier K-tile. All reads (A-quads AND B-frags)
// drain under a preceding MFMA burst via counted lgkm; B double-buffered,
// A-quads in 2 rotating buffers (net frag VGPR unchanged vs R6 = 96).
// Barriers: BAR(a) after P1 drain (B-stage safety), BAR(c) after P4 vmcnt
// (residency handoff). Full hazard ledger in comments.
// ---------------------------------------------------------------------------

typedef __attribute__((ext_vector_type(8))) short bf16x8;
typedef __attribute__((ext_vector_type(4))) float f32x4;
typedef __attribute__((ext_vector_type(8))) unsigned short u16x8;

__device__ __forceinline__ unsigned short f2bf(float x) {
  union { float f; unsigned u; } v; v.f = x;
  unsigned u = v.u;
  return (unsigned short)((u + 0x7FFFu + ((u >> 16) & 1u)) >> 16); // RNE
}

__global__ __launch_bounds__(256) void cvt_a_kernel(const float* __restrict__ in,
                                                    unsigned short* __restrict__ out) {
  long i = (long)blockIdx.x * 256 + threadIdx.x;
  const float4* in4 = (const float4*)in;
  float4 a = in4[2 * i];
  float4 b = in4[2 * i + 1];
  u16x8 r;
  r[0] = f2bf(a.x); r[1] = f2bf(a.y); r[2] = f2bf(a.z); r[3] = f2bf(a.w);
  r[4] = f2bf(b.x); r[5] = f2bf(b.y); r[6] = f2bf(b.z); r[7] = f2bf(b.w);
  ((u16x8*)out)[i] = r;
}

__global__ __launch_bounds__(256) void cvt_w_kernel(const int* __restrict__ in,
                                                    unsigned short* __restrict__ out) {
  long i = (long)blockIdx.x * 256 + threadIdx.x;
  int4 a = ((const int4*)in)[2 * i];
  int4 b = ((const int4*)in)[2 * i + 1];
  u16x8 r;
  r[0] = f2bf((float)a.x); r[1] = f2bf((float)a.y);
  r[2] = f2bf((float)a.z); r[3] = f2bf((float)a.w);
  r[4] = f2bf((float)b.x); r[5] = f2bf((float)b.y);
  r[6] = f2bf((float)b.z); r[7] = f2bf((float)b.w);
  ((u16x8*)out)[i] = r;
}

__device__ __forceinline__ void gl_lds16(const void* g, void* l) {
  __builtin_amdgcn_global_load_lds(
      (const __attribute__((address_space(1))) void*)g,
      (__attribute__((address_space(3))) void*)l,
      16, 0, 0);
}

__device__ __forceinline__ void stage2(const unsigned short* src, size_t K8,
                                       unsigned short* dst) {
  gl_lds16(src, dst);
  gl_lds16(src + K8, dst + 512);
}

#define WAIT_LGKM(N) do { asm volatile("s_waitcnt lgkmcnt(" #N ")" ::: "memory"); \
                          __builtin_amdgcn_sched_barrier(0); } while (0)
#define WAIT_VM(N)   asm volatile("s_waitcnt vmcnt(" #N ")" ::: "memory")
#define BAR()        do { asm volatile("" ::: "memory"); \
                          __builtin_amdgcn_s_barrier(); \
                          asm volatile("" ::: "memory"); } while (0)
#define SBAR0()      __builtin_amdgcn_sched_barrier(0)

#define BM 256
#define BN 256
#define BKT 64
#define HELEMS (128 * 64)   // one half-tile: 128 rows x 64 k = 16384 B

template <int MI0>
__device__ __forceinline__ void mfma_quad(f32x4 (&acc)[8][4],
                                          const bf16x8 (&a)[2][2],
                                          const bf16x8 (&b)[4][2]) {
  __builtin_amdgcn_s_setprio(1);
#pragma unroll
  for (int m = 0; m < 2; ++m)
#pragma unroll
    for (int ni = 0; ni < 4; ++ni)
#pragma unroll
      for (int kk = 0; kk < 2; ++kk)
        acc[MI0 + m][ni] = __builtin_amdgcn_mfma_f32_16x16x32_bf16(
            a[m][kk], b[ni][kk], acc[MI0 + m][ni], 0, 0, 0);
  __builtin_amdgcn_s_setprio(0);
}

// A-quad read (4 ds_read_b128 at precomputed base + compile-time immediates)
#define RD_AQ(dst, Pq, MI0)                                                  \
  do {                                                                       \
    dst[0][0] = *(const bf16x8*)(ldsB + offA[Pq][0] + (MI0) * 2048);         \
    dst[0][1] = *(const bf16x8*)(ldsB + offA[Pq][1] + (MI0) * 2048);         \
    dst[1][0] = *(const bf16x8*)(ldsB + offA[Pq][0] + (MI0 + 1) * 2048);     \
    dst[1][1] = *(const bf16x8*)(ldsB + offA[Pq][1] + (MI0 + 1) * 2048);     \
  } while (0)

// B-frag read: 8 ds_read_b128 from buf Pq
#define RD_B(dst, Pq)                                                        \
  do {                                                                       \
    _Pragma("unroll")                                                        \
    for (int ni = 0; ni < 4; ++ni) {                                         \
      dst[ni][0] = *(const bf16x8*)(ldsB + offB[Pq][0] + ni * 2048);         \
      dst[ni][1] = *(const bf16x8*)(ldsB + offB[Pq][1] + ni * 2048);         \
    }                                                                        \
  } while (0)

// One K-tile, 2 barriers. BC = current B regs, BN_ = next-tile B regs.
// Reads: P1 q1->aY, P2 q2->aX, P3 q3->aY, P4 B'(8)+q0'(4)->BN_,aX.
// Stages: P1 A1(u+1); P2 B0(u+2); P3 B1(u+2); P4 A0(u+2) (post-BAR).
// Hazard ledger:
//  - B0/B1(u+2) stages: B(u) readers drained @P1 lgkm(4), BAR(a) after. SAFE
//  - A1(u+1) stage: buf[p^1] A readers (tile u-1) drained @P3(u-1) lgkm(0),
//    BAR(c)(u-1) after. SAFE
//  - A0(u+2) stage (post-BAR(c)): all A(u)-readers drained @P3 lgkm(0),
//    which precedes BAR(c) in program order for every wave. SAFE
//  - P4 reads (tile u+1): residency via vmcnt(4) (drains A0(u+1)@P4(u-1),
//    A1(u+1)@P1(u); B(u+1) staged @P2/P3(u-1), older, drained) + BAR(c). SAFE
//  - steady-state gl_lds in flight at P4 vmcnt: A0(u+1),A1(u+1),B0(u+2),
//    B1(u+2) = 8 ops -> vmcnt(4) keeps B0B1(u+2). Tails conservative.
#define KT(U, P, BC, BN_)                                                     \
  do {                                                                        \
    const int u_ = (U);                                                       \
    /* P1 */                                                                  \
    RD_AQ(aY, P, 2);                                                          \
    if (u_ + 1 < NT)                                                          \
      stage2(gA_lane + K128 + (size_t)(u_ + 1) * BKT, K8,                     \
             (unsigned short*)(ldsB + (((P ^ 1) * 4 + 1) * 16384) + stOffB)); \
    WAIT_LGKM(4); /* drain B'(8)+q0'(4) (issued pre-quad3), keep q1 */        \
    BAR();        /* BAR(a) */                                                \
    mfma_quad<0>(acc, aX, BC);                                                \
    /* P2 */                                                                  \
    RD_AQ(aX, P, 4);                                                          \
    if (u_ + 2 < NT)                                                          \
      stage2(gB_lane + (size_t)(u_ + 2) * BKT, K8,                            \
             (unsigned short*)(ldsB + (((P) * 4 + 2) * 16384) + stOffB));     \
    WAIT_LGKM(4); /* drain q1, keep q2 */                                     \
    mfma_quad<2>(acc, aY, BC);                                                \
    /* P3 */                                                                  \
    RD_AQ(aY, P, 6);                                                          \
    if (u_ + 2 < NT)                                                          \
      stage2(gB_lane + K128 + (size_t)(u_ + 2) * BKT, K8,                     \
             (unsigned short*)(ldsB + (((P) * 4 + 3) * 16384) + stOffB));     \
    WAIT_LGKM(4); /* drain q2, keep q3 */                                     \
    mfma_quad<4>(acc, aX, BC);                                                \
    WAIT_LGKM(0); /* drain q3 before anyone stages A0(u+2) (post-BAR) */      \
    /* P4 */                                                                  \
    if (u_ < NT - 1) {                                                        \
      if (u_ + 2 < NT) { WAIT_VM(4); } else { WAIT_VM(0); }                   \
    }                                                                         \
    BAR();        /* BAR(c) */                                                \
    if (u_ + 2 < NT)                                                          \
      stage2(gA_lane + (size_t)(u_ + 2) * BKT, K8,                            \
             (unsigned short*)(ldsB + (((P) * 4 + 0) * 16384) + stOffB));     \
    if (u_ + 1 < NT) {                                                        \
      RD_B(BN_, (P) ^ 1);                                                     \
      RD_AQ(aX, (P) ^ 1, 0);                                                  \
    }                                                                         \
    mfma_quad<6>(acc, aY, BC);                                                \
  } while (0)

__global__ __launch_bounds__(512, 2) void gemm8_kernel(
    const unsigned short* __restrict__ A,   // [M,K] bf16
    const unsigned short* __restrict__ Wt,  // [N,K] bf16
    const float* __restrict__ scales,       // [N]
    const float* __restrict__ bias,         // [N]
    float* __restrict__ out,                // [M,N] fp32
    int M, int N, int K) {
  // [buf][A=0/B=1][half]; byte offset = (buf*4 + op*2 + half)*16384
  __shared__ unsigned short lds[2][2][2][HELEMS];
  char* ldsB = (char*)&lds[0][0][0][0];

  const int tid = threadIdx.x;
  const int lane = tid & 63;
  const int w = tid >> 6;      // wave 0..7
  const int wr = w >> 2;       // 0..1 (M)
  const int wc = w & 3;        // 0..3 (N)
  const int r = lane & 15;
  const int q4 = lane >> 4;
  const int NT = K / BKT;

  // Supertile XCD swizzle (per-XCD 1 tile_m x 16 tile_n strip)
  const int nm = M / BM, nn_t = N / BN;
  const int nwg = gridDim.x;
  const int bid = blockIdx.x;
  int tile_m, tile_n;
  if (nm == 32 && nn_t == 16 && nwg == 512) {
    int xcd = bid & 7;
    int j = bid >> 3;
    tile_m = (j >> 4) * 8 + xcd;
    tile_n = j & 15;
  } else {
    int swz = bid;
    if ((nwg & 7) == 0) swz = (bid & 7) * (nwg >> 3) + (bid >> 3);
    tile_m = swz % nm;
    tile_n = swz / nm;
  }
  const int bm = tile_m * BM;
  const int bn = tile_n * BN;

  // Precomputed swizzled LDS read bases (byte offsets from ldsB):
  // (row*128+col) ^ ((row&7)<<4)  ==  base + F*2048 + lk_kk  (verified R5)
  const int lk0 = r * 128 + ((q4 ^ (r & 3)) << 4) + ((((r >> 2) & 1)) << 6);
  const int lk1 = r * 128 + ((q4 ^ (r & 3)) << 4) + ((1 ^ ((r >> 2) & 1)) << 6);
  int offA[2][2], offB[2][2];
#pragma unroll
  for (int p = 0; p < 2; ++p) {
    offA[p][0] = (p * 4 + wr) * 16384 + lk0;
    offA[p][1] = (p * 4 + wr) * 16384 + lk1;
    offB[p][0] = (p * 4 + 2 + (wc >> 1)) * 16384 + (wc & 1) * 8192 + lk0;
    offB[p][1] = (p * 4 + 2 + (wc >> 1)) * 16384 + (wc & 1) * 8192 + lk1;
  }

  // Staging lane constants (linear LDS dest + inverse-swizzled global src)
  const int rl = lane >> 3;
  const int gs = (lane & 7) ^ (rl & 7);
  const int stOffB = w * 2048 + lane * 16;
  const size_t K8 = (size_t)8 * K;
  const size_t K128 = (size_t)128 * K;
  const unsigned short* gA_lane = A + (size_t)bm * K + (size_t)(w * 16 + rl) * K + gs * 8;
  const unsigned short* gB_lane = Wt + (size_t)bn * K + (size_t)(w * 16 + rl) * K + gs * 8;

  // ---- prologue: tile0 {A0,A1,B0,B1} + tile1 {B0,B1}; vm(4); BAR;
  //      then "P4(-1)": stage A0(1), read B(0)+q0(0) ----------------------
  stage2(gA_lane,              K8, (unsigned short*)(ldsB + 0 * 16384 + stOffB));
  stage2(gA_lane + K128,       K8, (unsigned short*)(ldsB + 1 * 16384 + stOffB));
  stage2(gB_lane,              K8, (unsigned short*)(ldsB + 2 * 16384 + stOffB));
  stage2(gB_lane + K128,       K8, (unsigned short*)(ldsB + 3 * 16384 + stOffB));
  stage2(gB_lane + BKT,        K8, (unsigned short*)(ldsB + 6 * 16384 + stOffB));
  stage2(gB_lane + K128 + BKT, K8, (unsigned short*)(ldsB + 7 * 16384 + stOffB));
  WAIT_VM(4);   // tile0 resident; keep B0B1(1) in flight
  BAR();
  stage2(gA_lane + BKT,        K8, (unsigned short*)(ldsB + 4 * 16384 + stOffB));

  f32x4 acc[8][4] = {};
  bf16x8 bfrE[4][2], bfrO[4][2];
  bf16x8 aX[2][2], aY[2][2];

  RD_B(bfrE, 0);     // tile0 B frags (drain at P1(0) lgkm(4))
  RD_AQ(aX, 0, 0);   // tile0 quad0

  for (int t = 0; t < NT; t += 2) {
    KT(t,     0, bfrE, bfrO);
    KT(t + 1, 1, bfrO, bfrE);
  }

  // ---- epilogue: out = acc * scales + bias --------------------------------
  float sc[4], bs[4];
#pragma unroll
  for (int ni = 0; ni < 4; ++ni) {
    int col = bn + wc * 64 + ni * 16 + r;
    sc[ni] = scales[col];
    bs[ni] = bias[col];
  }
#pragma unroll
  for (int mi = 0; mi < 8; ++mi)
#pragma unroll
    for (int ni = 0; ni < 4; ++ni)
#pragma unroll
      for (int i = 0; i < 4; ++i) {
        int grow = bm + wr * 128 + mi * 16 + q4 * 4 + i;
        int gcol = bn + wc * 64 + ni * 16 + r;
        out[(size_t)grow * N + gcol] = acc[mi][ni][i] * sc[ni] + bs[ni];
      }
}

// ---- fallback (correct but slow) ------------------------------------------
__global__ __launch_bounds__(256) void naive_kernel(
    const float* __restrict__ A, const int* __restrict__ W8,
    const float* __restrict__ scales, const float* __restrict__ bias,
    float* __restrict__ out, int M, int N, int K) {
  long idx = (long)blockIdx.x * 256 + threadIdx.x;
  if (idx >= (long)M * N) return;
  int m = (int)(idx / N), n = (int)(idx % N);
  const float* a = A + (size_t)m * K;
  const int* wv = W8 + (size_t)n * K;
  float s = 0.f;
  for (int k = 0; k < K; ++k) s += a[k] * (float)wv[k];
  out[idx] = s * scales[n] + bias[n];
}

extern "C" void kernel_launch(void* const* d_in, const int* in_sizes, int n_in,
                              void* d_out, int out_size, void* d_ws, size_t ws_size,
                              hipStream_t stream) {
  const float* A = (const float*)d_in[0];
  const int* W8 = (const int*)d_in[1];
  const float* scales = (const float*)d_in[2];
  const float* bias = (const float*)d_in[3];
  float* out = (float*)d_out;

  const int N = in_sizes[2];
  const int K = in_sizes[1] / N;
  const int M = in_sizes[0] / K;

  size_t a_bytes = (size_t)M * K * 2;
  size_t w_bytes = (size_t)N * K * 2;
  const int NT = K / BKT;

  bool tiled_ok = (M % BM == 0) && (N % BN == 0) && (K % BKT == 0) &&
                  (NT >= 4) && (NT % 2 == 0) && (ws_size >= a_bytes + w_bytes);

  if (!tiled_ok) {
    long total = (long)M * N;
    naive_kernel<<<(unsigned)((total + 255) / 256), 256, 0, stream>>>(
        A, W8, scales, bias, out, M, N, K);
    return;
  }

  unsigned short* Abf = (unsigned short*)d_ws;
  unsigned short* Wbf = (unsigned short*)((char*)d_ws + a_bytes);

  long nA = (long)M * K;
  long nW = (long)N * K;
  cvt_a_kernel<<<(unsigned)(nA / 2048), 256, 0, stream>>>(A, Abf);
  cvt_w_kernel<<<(unsigned)(nW / 2048), 256, 0, stream>>>(W8, Wbf);

  unsigned nwg = (unsigned)((M / BM) * (N / BN));  // 512
  gemm8_kernel<<<nwg, 512, 0, stream>>>(Abf, Wbf, scales, bias, out, M, N, K);
}

// Round 8
// 273.511 us; speedup vs baseline: 2.2209x; 2.2209x over previous
//
#include <hip/hip_runtime.h>
#include <hip/hip_bf16.h>
#include <stdint.h>

// ---------------------------------------------------------------------------
// W8A16 linear: out[M,N] = (A[M,K] fp32) x (W[N,K] int8->bf16)^T * scales[N] + bias[N]
// M=8192, N=4096, K=4096.  Prepass converts A,W -> bf16 in d_ws, then a
// 256x256-tile GEMM. R8: 2-barrier K-tile (R7 schedule) with SINGLE-buffered
// B-frags (R7's spill fix): B(u+1) read at P4 after quad3 consumes old bfr,
// order pinned by sched_barrier so regalloc reuses the registers.
// ---------------------------------------------------------------------------

typedef __attribute__((ext_vector_type(8))) short bf16x8;
typedef __attribute__((ext_vector_type(4))) float f32x4;
typedef __attribute__((ext_vector_type(8))) unsigned short u16x8;

__device__ __forceinline__ unsigned short f2bf(float x) {
  union { float f; unsigned u; } v; v.f = x;
  unsigned u = v.u;
  return (unsigned short)((u + 0x7FFFu + ((u >> 16) & 1u)) >> 16); // RNE
}

__global__ __launch_bounds__(256) void cvt_a_kernel(const float* __restrict__ in,
                                                    unsigned short* __restrict__ out) {
  long i = (long)blockIdx.x * 256 + threadIdx.x;
  const float4* in4 = (const float4*)in;
  float4 a = in4[2 * i];
  float4 b = in4[2 * i + 1];
  u16x8 r;
  r[0] = f2bf(a.x); r[1] = f2bf(a.y); r[2] = f2bf(a.z); r[3] = f2bf(a.w);
  r[4] = f2bf(b.x); r[5] = f2bf(b.y); r[6] = f2bf(b.z); r[7] = f2bf(b.w);
  ((u16x8*)out)[i] = r;
}

__global__ __launch_bounds__(256) void cvt_w_kernel(const int* __restrict__ in,
                                                    unsigned short* __restrict__ out) {
  long i = (long)blockIdx.x * 256 + threadIdx.x;
  int4 a = ((const int4*)in)[2 * i];
  int4 b = ((const int4*)in)[2 * i + 1];
  u16x8 r;
  r[0] = f2bf((float)a.x); r[1] = f2bf((float)a.y);
  r[2] = f2bf((float)a.z); r[3] = f2bf((float)a.w);
  r[4] = f2bf((float)b.x); r[5] = f2bf((float)b.y);
  r[6] = f2bf((float)b.z); r[7] = f2bf((float)b.w);
  ((u16x8*)out)[i] = r;
}

__device__ __forceinline__ void gl_lds16(const void* g, void* l) {
  __builtin_amdgcn_global_load_lds(
      (const __attribute__((address_space(1))) void*)g,
      (__attribute__((address_space(3))) void*)l,
      16, 0, 0);
}

__device__ __forceinline__ void stage2(const unsigned short* src, size_t K8,
                                       unsigned short* dst) {
  gl_lds16(src, dst);
  gl_lds16(src + K8, dst + 512);
}

#define WAIT_LGKM(N) do { asm volatile("s_waitcnt lgkmcnt(" #N ")" ::: "memory"); \
                          __builtin_amdgcn_sched_barrier(0); } while (0)
#define WAIT_VM(N)   asm volatile("s_waitcnt vmcnt(" #N ")" ::: "memory")
#define BAR()        do { asm volatile("" ::: "memory"); \
                          __builtin_amdgcn_s_barrier(); \
                          asm volatile("" ::: "memory"); } while (0)
#define SBAR0()      __builtin_amdgcn_sched_barrier(0)

#define BM 256
#define BN 256
#define BKT 64
#define HELEMS (128 * 64)   // one half-tile: 128 rows x 64 k = 16384 B

template <int MI0>
__device__ __forceinline__ void mfma_quad(f32x4 (&acc)[8][4],
                                          const bf16x8 (&a)[2][2],
                                          const bf16x8 (&b)[4][2]) {
  __builtin_amdgcn_s_setprio(1);
#pragma unroll
  for (int m = 0; m < 2; ++m)
#pragma unroll
    for (int ni = 0; ni < 4; ++ni)
#pragma unroll
      for (int kk = 0; kk < 2; ++kk)
        acc[MI0 + m][ni] = __builtin_amdgcn_mfma_f32_16x16x32_bf16(
            a[m][kk], b[ni][kk], acc[MI0 + m][ni], 0, 0, 0);
  __builtin_amdgcn_s_setprio(0);
}

// A-quad read (4 ds_read_b128 at precomputed base + compile-time immediates)
#define RD_AQ(dst, Pq, MI0)                                                  \
  do {                                                                       \
    dst[0][0] = *(const bf16x8*)(ldsB + offA[Pq][0] + (MI0) * 2048);         \
    dst[0][1] = *(const bf16x8*)(ldsB + offA[Pq][1] + (MI0) * 2048);         \
    dst[1][0] = *(const bf16x8*)(ldsB + offA[Pq][0] + (MI0 + 1) * 2048);     \
    dst[1][1] = *(const bf16x8*)(ldsB + offA[Pq][1] + (MI0 + 1) * 2048);     \
  } while (0)

// B-frag read: 8 ds_read_b128 from buf Pq
#define RD_B(dst, Pq)                                                        \
  do {                                                                       \
    _Pragma("unroll")                                                        \
    for (int ni = 0; ni < 4; ++ni) {                                         \
      dst[ni][0] = *(const bf16x8*)(ldsB + offB[Pq][0] + ni * 2048);         \
      dst[ni][1] = *(const bf16x8*)(ldsB + offB[Pq][1] + ni * 2048);         \
    }                                                                        \
  } while (0)

// One K-tile, 2 barriers, single B buffer.
// Reads: P1 q1->aY, P2 q2->aX, P3 q3->aY, P4 q0'(u+1)->aX then (post-quad3)
//        B(u+1)->bfr (8). Drained at P1(u+1)'s lgkm(4).
// Stages: P1 A1(u+1); P2 B0(u+2); P3 B1(u+2); P4 A0(u+2) (post-BAR-c).
// Hazard ledger (verified):
//  - B0/B1(u+2)@P2/P3: B(u) readers (RD_B @P4(u-1)) drained @P1 lgkm(4),
//    BAR(a) after. SAFE
//  - A1(u+1)@P1: A1(u-1) readers (wr=1 q0..q3) drained @P3(u-1) lgkm(0),
//    BAR(c)(u-1) after. SAFE
//  - A0(u+2)@P4 post-BAR(c): A0(u) readers drained @P3 lgkm(0), which
//    precedes BAR(c) in every wave's program order. SAFE
//  - P4 reads of tile u+1: vmcnt(4) [12 in flight: B(u+1)@P2/P3(u-1),
//    A0(u+1)@P4(u-1), A1(u+1)@P1(u), B(u+2)@P2/P3(u)] drains tile u+1's 8;
//    BAR(c) makes it cross-wave. SAFE
//  - bfr WAR: RD_B emitted after quad3 (SBAR0 pin) -> regalloc reuses regs.
#define KT(U, P)                                                              \
  do {                                                                        \
    const int u_ = (U);                                                       \
    /* P1 */                                                                  \
    RD_AQ(aY, P, 2);                                                          \
    if (u_ + 1 < NT)                                                          \
      stage2(gA_lane + K128 + (size_t)(u_ + 1) * BKT, K8,                     \
             (unsigned short*)(ldsB + (((P ^ 1) * 4 + 1) * 16384) + stOffB)); \
    WAIT_LGKM(4); /* drain q0'(4)+B(8), keep q1 */                            \
    BAR();        /* BAR(a) */                                                \
    mfma_quad<0>(acc, aX, bfr);                                               \
    /* P2 */                                                                  \
    RD_AQ(aX, P, 4);                                                          \
    if (u_ + 2 < NT)                                                          \
      stage2(gB_lane + (size_t)(u_ + 2) * BKT, K8,                            \
             (unsigned short*)(ldsB + (((P) * 4 + 2) * 16384) + stOffB));     \
    WAIT_LGKM(4); /* drain q1, keep q2 */                                     \
    mfma_quad<2>(acc, aY, bfr);                                               \
    /* P3 */                                                                  \
    RD_AQ(aY, P, 6);                                                          \
    if (u_ + 2 < NT)                                                          \
      stage2(gB_lane + K128 + (size_t)(u_ + 2) * BKT, K8,                     \
             (unsigned short*)(ldsB + (((P) * 4 + 3) * 16384) + stOffB));     \
    WAIT_LGKM(4); /* drain q2, keep q3 */                                     \
    mfma_quad<4>(acc, aX, bfr);                                               \
    WAIT_LGKM(0); /* drain q3 (before A0(u+2) stage post-BAR) */              \
    /* P4 */                                                                  \
    if (u_ + 2 < NT)      { WAIT_VM(4); }                                     \
    else if (u_ + 1 < NT) { WAIT_VM(0); }                                     \
    BAR();        /* BAR(c): tile u+1 resident for all waves */               \
    if (u_ + 2 < NT)                                                          \
      stage2(gA_lane + (size_t)(u_ + 2) * BKT, K8,                            \
             (unsigned short*)(ldsB + (((P) * 4 + 0) * 16384) + stOffB));     \
    if (u_ + 1 < NT) RD_AQ(aX, (P) ^ 1, 0);                                   \
    SBAR0();                                                                  \
    mfma_quad<6>(acc, aY, bfr);                                               \
    SBAR0(); /* pin: RD_B after quad3 so bfr regs are reused, not renamed */  \
    if (u_ + 1 < NT) RD_B(bfr, (P) ^ 1);                                      \
  } while (0)

__global__ __launch_bounds__(512, 2) void gemm8_kernel(
    const unsigned short* __restrict__ A,   // [M,K] bf16
    const unsigned short* __restrict__ Wt,  // [N,K] bf16
    const float* __restrict__ scales,       // [N]
    const float* __restrict__ bias,         // [N]
    float* __restrict__ out,                // [M,N] fp32
    int M, int N, int K) {
  // [buf][A=0/B=1][half]; byte offset = (buf*4 + op*2 + half)*16384
  __shared__ unsigned short lds[2][2][2][HELEMS];
  char* ldsB = (char*)&lds[0][0][0][0];

  const int tid = threadIdx.x;
  const int lane = tid & 63;
  const int w = tid >> 6;      // wave 0..7
  const int wr = w >> 2;       // 0..1 (M)
  const int wc = w & 3;        // 0..3 (N)
  const int r = lane & 15;
  const int q4 = lane >> 4;
  const int NT = K / BKT;

  // Supertile XCD swizzle (per-XCD 1 tile_m x 16 tile_n strip)
  const int nm = M / BM, nn_t = N / BN;
  const int nwg = gridDim.x;
  const int bid = blockIdx.x;
  int tile_m, tile_n;
  if (nm == 32 && nn_t == 16 && nwg == 512) {
    int xcd = bid & 7;
    int j = bid >> 3;
    tile_m = (j >> 4) * 8 + xcd;
    tile_n = j & 15;
  } else {
    int swz = bid;
    if ((nwg & 7) == 0) swz = (bid & 7) * (nwg >> 3) + (bid >> 3);
    tile_m = swz % nm;
    tile_n = swz / nm;
  }
  const int bm = tile_m * BM;
  const int bn = tile_n * BN;

  // Precomputed swizzled LDS read bases (byte offsets from ldsB):
  // (row*128+col) ^ ((row&7)<<4)  ==  base + F*2048 + lk_kk  (verified R5)
  const int lk0 = r * 128 + ((q4 ^ (r & 3)) << 4) + ((((r >> 2) & 1)) << 6);
  const int lk1 = r * 128 + ((q4 ^ (r & 3)) << 4) + ((1 ^ ((r >> 2) & 1)) << 6);
  int offA[2][2], offB[2][2];
#pragma unroll
  for (int p = 0; p < 2; ++p) {
    offA[p][0] = (p * 4 + wr) * 16384 + lk0;
    offA[p][1] = (p * 4 + wr) * 16384 + lk1;
    offB[p][0] = (p * 4 + 2 + (wc >> 1)) * 16384 + (wc & 1) * 8192 + lk0;
    offB[p][1] = (p * 4 + 2 + (wc >> 1)) * 16384 + (wc & 1) * 8192 + lk1;
  }

  // Staging lane constants (linear LDS dest + inverse-swizzled global src)
  const int rl = lane >> 3;
  const int gs = (lane & 7) ^ (rl & 7);
  const int stOffB = w * 2048 + lane * 16;
  const size_t K8 = (size_t)8 * K;
  const size_t K128 = (size_t)128 * K;
  const unsigned short* gA_lane = A + (size_t)bm * K + (size_t)(w * 16 + rl) * K + gs * 8;
  const unsigned short* gB_lane = Wt + (size_t)bn * K + (size_t)(w * 16 + rl) * K + gs * 8;

  // ---- prologue: tile0 {A0,A1,B0,B1} + tile1 {B0,B1,A0}; vm(6); BAR;
  //      then steady-state entry reads q0(0)+B(0) ---------------------------
  stage2(gA_lane,              K8, (unsigned short*)(ldsB + 0 * 16384 + stOffB));
  stage2(gA_lane + K128,       K8, (unsigned short*)(ldsB + 1 * 16384 + stOffB));
  stage2(gB_lane,              K8, (unsigned short*)(ldsB + 2 * 16384 + stOffB));
  stage2(gB_lane + K128,       K8, (unsigned short*)(ldsB + 3 * 16384 + stOffB));
  stage2(gB_lane + BKT,        K8, (unsigned short*)(ldsB + 6 * 16384 + stOffB));
  stage2(gB_lane + K128 + BKT, K8, (unsigned short*)(ldsB + 7 * 16384 + stOffB));
  stage2(gA_lane + BKT,        K8, (unsigned short*)(ldsB + 4 * 16384 + stOffB));
  WAIT_VM(6);   // tile0 resident; keep B0B1(1)+A0(1) in flight (matches P4 out)
  BAR();

  f32x4 acc[8][4] = {};
  bf16x8 bfr[4][2];
  bf16x8 aX[2][2], aY[2][2];

  RD_AQ(aX, 0, 0);   // tile0 quad0  (drains at P1(0) lgkm(4))
  RD_B(bfr, 0);      // tile0 B frags

  for (int t = 0; t < NT; t += 2) {
    KT(t, 0);
    KT(t + 1, 1);
  }

  // ---- epilogue: out = acc * scales + bias --------------------------------
  float sc[4], bs[4];
#pragma unroll
  for (int ni = 0; ni < 4; ++ni) {
    int col = bn + wc * 64 + ni * 16 + r;
    sc[ni] = scales[col];
    bs[ni] = bias[col];
  }
#pragma unroll
  for (int mi = 0; mi < 8; ++mi)
#pragma unroll
    for (int ni = 0; ni < 4; ++ni)
#pragma unroll
      for (int i = 0; i < 4; ++i) {
        int grow = bm + wr * 128 + mi * 16 + q4 * 4 + i;
        int gcol = bn + wc * 64 + ni * 16 + r;
        out[(size_t)grow * N + gcol] = acc[mi][ni][i] * sc[ni] + bs[ni];
      }
}

// ---- fallback (correct but slow) ------------------------------------------
__global__ __launch_bounds__(256) void naive_kernel(
    const float* __restrict__ A, const int* __restrict__ W8,
    const float* __restrict__ scales, const float* __restrict__ bias,
    float* __restrict__ out, int M, int N, int K) {
  long idx = (long)blockIdx.x * 256 + threadIdx.x;
  if (idx >= (long)M * N) return;
  int m = (int)(idx / N), n = (int)(idx % N);
  const float* a = A + (size_t)m * K;
  const int* wv = W8 + (size_t)n * K;
  float s = 0.f;
  for (int k = 0; k < K; ++k) s += a[k] * (float)wv[k];
  out[idx] = s * scales[n] + bias[n];
}

extern "C" void kernel_launch(void* const* d_in, const int* in_sizes, int n_in,
                              void* d_out, int out_size, void* d_ws, size_t ws_size,
                              hipStream_t stream) {
  const float* A = (const float*)d_in[0];
  const int* W8 = (const int*)d_in[1];
  const float* scales = (const float*)d_in[2];
  const float* bias = (const float*)d_in[3];
  float* out = (float*)d_out;

  const int N = in_sizes[2];
  const int K = in_sizes[1] / N;
  const int M = in_sizes[0] / K;

  size_t a_bytes = (size_t)M * K * 2;
  size_t w_bytes = (size_t)N * K * 2;
  const int NT = K / BKT;

  bool tiled_ok = (M % BM == 0) && (N % BN == 0) && (K % BKT == 0) &&
                  (NT >= 4) && (NT % 2 == 0) && (ws_size >= a_bytes + w_bytes);

  if (!tiled_ok) {
    long total = (long)M * N;
    naive_kernel<<<(unsigned)((total + 255) / 256), 256, 0, stream>>>(
        A, W8, scales, bias, out, M, N, K);
    return;
  }

  unsigned short* Abf = (unsigned short*)d_ws;
  unsigned short* Wbf = (unsigned short*)((char*)d_ws + a_bytes);

  long nA = (long)M * K;
  long nW = (long)N * K;
  cvt_a_kernel<<<(unsigned)(nA / 2048), 256, 0, stream>>>(A, Abf);
  cvt_w_kernel<<<(unsigned)(nW / 2048), 256, 0, stream>>>(W8, Wbf);

  unsigned nwg = (unsigned)((M / BM) * (N / BN));  // 512
  gemm8_kernel<<<nwg, 512, 0, stream>>>(Abf, Wbf, scales, bias, out, M, N, K);
}